// Round 2
// baseline (3466.108 us; speedup 1.0000x reference)
//
#include <hip/hip_runtime.h>
#include <hip/hip_cooperative_groups.h>

namespace cg = cooperative_groups;

typedef __attribute__((ext_vector_type(8))) short short8;
typedef __attribute__((ext_vector_type(4))) float f32x4;

__device__ __forceinline__ float bf2f(ushort u) {
  union { unsigned int i; float f; } x; x.i = ((unsigned int)u) << 16; return x.f;
}
__device__ __forceinline__ ushort f2bf(float f) {
  union { float f; unsigned int i; } x; x.f = f;
  unsigned int i = x.i + 0x7fffu + ((x.i >> 16) & 1u);
  return (ushort)(i >> 16);
}
__device__ __forceinline__ float fast_tanh(float x) {
  x = fminf(fmaxf(x, -15.f), 15.f);
  float e = __expf(2.f * x);
  return __fdividef(e - 1.f, e + 1.f);
}

// -------- transpose fp32 -> bf16, out[c][r] = bf16(in[r][c]) --------
__global__ void transpose_f2b(const float* __restrict__ in, ushort* __restrict__ out,
                              int R, int C) {
  __shared__ ushort tile[32][33];
  int c0 = blockIdx.x * 32, r0 = blockIdx.y * 32;
  int tx = threadIdx.x, ty = threadIdx.y;  // block (32,8)
  for (int i = 0; i < 32; i += 8) {
    int r = r0 + ty + i, c = c0 + tx;
    if (r < R && c < C) tile[ty + i][tx] = f2bf(in[(size_t)r * C + c]);
  }
  __syncthreads();
  for (int i = 0; i < 32; i += 8) {
    int c = c0 + ty + i, r = r0 + tx;
    if (r < R && c < C) out[(size_t)c * R + r] = tile[tx][ty + i];
  }
}

// -------- gather embedded tokens (fp32 emb -> bf16): embA[t*128+b][:] --------
__global__ void embed_gather(const int* __restrict__ target, const float* __restrict__ emb,
                             ushort* __restrict__ embA) {
  int m = blockIdx.x;            // 0..6015
  int t = m >> 7, b = m & 127;
  int tok = (t == 0) ? 1 : target[b * 48 + t];
  embA[(size_t)m * 256 + threadIdx.x] = f2bf(emb[(size_t)tok * 256 + threadIdx.x]);
}

// ---------------- 128x128 LDS-staged MFMA GEMM (m93 pattern, reg-staged) ----------------
// C = act(A[M,K] @ BT[NrowsB,K]^T + bias).  M must be a multiple of 128.
// flags: 1=relu, 2=store fp32, 4=remap rows m=t*128+b -> out row b*47+t, 8=A is fp32
__global__ __launch_bounds__(256) void gemm128(
    const void* __restrict__ Ap, const ushort* __restrict__ BT,
    const float* __restrict__ bias, void* __restrict__ Cout,
    int M, int N, int K, int NrowsB, int flags) {
  __shared__ ushort lA[128 * 32];
  __shared__ ushort lB[128 * 32];
  int tid = threadIdx.x;
  int wave = tid >> 6, lane = tid & 63;
  int q = lane >> 4, l16 = lane & 15;
  int wr = wave >> 1, wc = wave & 1;
  int m0 = blockIdx.y * 128, n0 = blockIdx.x * 128;
  f32x4 acc[4][4];
#pragma unroll
  for (int i = 0; i < 4; ++i)
#pragma unroll
    for (int j = 0; j < 4; ++j) acc[i][j] = (f32x4){0.f, 0.f, 0.f, 0.f};
  // staging: thread loads chunks tid and tid+256 (8 ushorts each); chunk c -> row c>>2, col (c&3)*8
  int r0 = tid >> 2, cc0 = (tid & 3) * 8;
  int r1 = r0 + 64, cc1 = cc0;
  int rb0 = n0 + r0; if (rb0 >= NrowsB) rb0 = NrowsB - 1;
  int rb1 = n0 + r1; if (rb1 >= NrowsB) rb1 = NrowsB - 1;
  for (int k = 0; k < K; k += 32) {
    short8 va0, va1, vb0, vb1;
    if (flags & 8) {
      const float* s0 = (const float*)Ap + (size_t)(m0 + r0) * K + k + cc0;
      const float* s1 = (const float*)Ap + (size_t)(m0 + r1) * K + k + cc1;
      short8 t0, t1;
#pragma unroll
      for (int e = 0; e < 8; ++e) { t0[e] = (short)f2bf(s0[e]); t1[e] = (short)f2bf(s1[e]); }
      va0 = t0; va1 = t1;
    } else {
      va0 = *(const short8*)((const ushort*)Ap + (size_t)(m0 + r0) * K + k + cc0);
      va1 = *(const short8*)((const ushort*)Ap + (size_t)(m0 + r1) * K + k + cc1);
    }
    vb0 = *(const short8*)(BT + (size_t)rb0 * K + k + cc0);
    vb1 = *(const short8*)(BT + (size_t)rb1 * K + k + cc1);
    __syncthreads();   // previous iter's ds_reads complete before overwrite
    *(short8*)&lA[r0 * 32 + cc0] = va0;
    *(short8*)&lA[r1 * 32 + cc1] = va1;
    *(short8*)&lB[r0 * 32 + cc0] = vb0;
    *(short8*)&lB[r1 * 32 + cc1] = vb1;
    __syncthreads();
    short8 af[4], bfr[4];
#pragma unroll
    for (int i = 0; i < 4; ++i)
      af[i] = *(const short8*)&lA[(wr * 64 + i * 16 + l16) * 32 + q * 8];
#pragma unroll
    for (int j = 0; j < 4; ++j)
      bfr[j] = *(const short8*)&lB[(wc * 64 + j * 16 + l16) * 32 + q * 8];
#pragma unroll
    for (int i = 0; i < 4; ++i)
#pragma unroll
      for (int j = 0; j < 4; ++j)
        acc[i][j] = __builtin_amdgcn_mfma_f32_16x16x32_bf16(af[i], bfr[j], acc[i][j], 0, 0, 0);
  }
#pragma unroll
  for (int i = 0; i < 4; ++i)
#pragma unroll
    for (int j = 0; j < 4; ++j)
#pragma unroll
      for (int r = 0; r < 4; ++r) {
        int gr = m0 + wr * 64 + i * 16 + q * 4 + r;  // D row = quad*4 + reg [m89/m91]
        int gc = n0 + wc * 64 + j * 16 + l16;        // D col = lane&15
        if (gc >= N) continue;
        float v = acc[i][j][r];
        if (bias) v += bias[gc];
        if (flags & 1) v = fmaxf(v, 0.f);
        size_t orow = (size_t)gr;
        if (flags & 4) { int t = gr >> 7, bb = gr & 127; orow = (size_t)bb * 47 + t; }
        if (flags & 2) ((float*)Cout)[orow * (size_t)N + gc] = v;
        else ((ushort*)Cout)[orow * (size_t)N + gc] = f2bf(v);
      }
}

// ---------------- persistent cooperative loop: 47 steps, 2 grid syncs each ----------------
// grid = 128 blocks x 256 threads (co-resident; 256 CUs).
// phase A: block b computes hid_w2 matvec + attention -> ctx[b]
// phase B: blocks 0..63 compute GRU gates via MFMA -> states[t+1]
__global__ __launch_bounds__(256) void step_loop(
    const ushort* __restrict__ featW1,    // (8192,512) bf16, row = b*64+l
    const ushort* __restrict__ features,  // (8192,256) bf16
    const ushort* __restrict__ W2T,       // (512,512) bf16, row u = col u of W2
    const float* __restrict__ b2,         // (512)
    const float* __restrict__ V,          // (512)
    const float* __restrict__ bV,         // (1)
    const ushort* __restrict__ embA,      // (6016,256) bf16, row = t*128+b
    const ushort* __restrict__ gruT,      // (1536,512) bf16
    const float* __restrict__ grub0,      // (1536)
    const float* __restrict__ grub1,      // (1536)
    ushort* states,                       // (48,128,512) bf16; [0] pre-zeroed
    ushort* ctx) {                        // (128,256) bf16 scratch
  cg::grid_group grid = cg::this_grid();
  int bid = blockIdx.x, tid = threadIdx.x;
  int wave = tid >> 6, lane = tid & 63;
  int q = lane >> 4, l16 = lane & 15, koff = q * 8;
  __shared__ __align__(16) float stf[512];
  __shared__ float hw2[512], Vv[512], sc[64], attnw[64];
  __shared__ float mx[3][32][33];
  Vv[tid] = V[tid];
  Vv[tid + 256] = V[tid + 256];

#pragma unroll 1
  for (int t = 0; t < 47; ++t) {
    // ---------------- phase A: attention for batch b = bid ----------------
    {
      int b = bid;
      const ushort* sr = states + (size_t)t * 128 * 512 + (size_t)b * 512;
      stf[tid] = bf2f(sr[tid]);
      stf[tid + 256] = bf2f(sr[tid + 256]);
      __syncthreads();
      // hw2[u] = state[b] . W2[:,u] + b2[u]
#pragma unroll 1
      for (int uu = 0; uu < 2; ++uu) {
        int u = tid + uu * 256;
        const short8* w = (const short8*)(W2T + (size_t)u * 512);
        float s = 0.f;
#pragma unroll 4
        for (int k8 = 0; k8 < 64; ++k8) {
          short8 wv = w[k8];
          const float4* sp = (const float4*)(stf + k8 * 8);
          float4 s0v = sp[0], s1v = sp[1];
          s += bf2f((ushort)wv[0]) * s0v.x + bf2f((ushort)wv[1]) * s0v.y +
               bf2f((ushort)wv[2]) * s0v.z + bf2f((ushort)wv[3]) * s0v.w +
               bf2f((ushort)wv[4]) * s1v.x + bf2f((ushort)wv[5]) * s1v.y +
               bf2f((ushort)wv[6]) * s1v.z + bf2f((ushort)wv[7]) * s1v.w;
        }
        hw2[u] = s + b2[u];
      }
      __syncthreads();
      // scores: 4 threads per region l, 128 u each (vectorized featW1 reads)
      int l = tid >> 2, part = tid & 3;
      const short8* fw8 = (const short8*)(featW1 + ((size_t)(b * 64 + l)) * 512 + part * 128);
      float s = 0.f;
#pragma unroll 2
      for (int u8 = 0; u8 < 16; ++u8) {
        short8 fv = fw8[u8];
        int ub = part * 128 + u8 * 8;
#pragma unroll
        for (int e = 0; e < 8; ++e) {
          float x = bf2f((ushort)fv[e]) + hw2[ub + e];
          s += fast_tanh(x) * Vv[ub + e];
        }
      }
      s += __shfl_xor(s, 1);
      s += __shfl_xor(s, 2);
      if (part == 0) sc[l] = s + bV[0];
      __syncthreads();
      if (tid < 64) {  // softmax over L=64, single wave
        float v = sc[tid], m = v;
        for (int o = 32; o; o >>= 1) m = fmaxf(m, __shfl_xor(m, o));
        float e = __expf(v - m), ssum = e;
        for (int o = 32; o; o >>= 1) ssum += __shfl_xor(ssum, o);
        attnw[tid] = e / ssum;
      }
      __syncthreads();
      float c = 0.f;
      const ushort* fb = features + (size_t)b * 64 * 256 + tid;
      for (int l2 = 0; l2 < 64; ++l2) c += attnw[l2] * bf2f(fb[l2 * 256]);
      ctx[(size_t)b * 256 + tid] = f2bf(c);
    }
    grid.sync();
    // ---------------- phase B: GRU gates, blocks 0..63 ----------------
    if (bid < 64) {
      int u0 = (bid & 15) * 32, b0 = (bid >> 4) * 32;
      const ushort* embAt = embA + (size_t)t * 128 * 256;
      if (wave < 3) {
        int n0g = wave * 512 + u0;  // gate wave: z, r(+512), h(+1024)
        f32x4 acc[2][2];
#pragma unroll
        for (int i = 0; i < 2; ++i)
#pragma unroll
          for (int j = 0; j < 2; ++j) acc[i][j] = (f32x4){0.f, 0.f, 0.f, 0.f};
        for (int k = 0; k < 512; k += 32) {
          short8 a2[2], bb[2];
#pragma unroll
          for (int i = 0; i < 2; ++i) {
            int row = b0 + i * 16 + l16;
            const ushort* src = (k < 256)
                ? (ctx   + (size_t)row * 256 + k + koff)
                : (embAt + (size_t)row * 256 + (k - 256) + koff);
            a2[i] = *(const short8*)src;
          }
#pragma unroll
          for (int j = 0; j < 2; ++j)
            bb[j] = *(const short8*)(gruT + (size_t)(n0g + j * 16 + l16) * 512 + k + koff);
#pragma unroll
          for (int i = 0; i < 2; ++i)
#pragma unroll
            for (int j = 0; j < 2; ++j)
              acc[i][j] = __builtin_amdgcn_mfma_f32_16x16x32_bf16(a2[i], bb[j], acc[i][j], 0, 0, 0);
        }
#pragma unroll
        for (int i = 0; i < 2; ++i)
#pragma unroll
          for (int j = 0; j < 2; ++j)
#pragma unroll
            for (int r = 0; r < 4; ++r) {
              int lr = i * 16 + q * 4 + r, lc = j * 16 + l16;
              mx[wave][lr][lc] = acc[i][j][r] + grub0[n0g + lc];
            }
      }
      __syncthreads();
      ushort* so = states + (size_t)(t + 1) * 128 * 512;
      for (int c = tid; c < 1024; c += 256) {
        int bl = c >> 5, ul = c & 31;
        int u = u0 + ul, b = b0 + bl;
        float xz = mx[0][bl][ul] + grub1[u];
        float xr = mx[1][bl][ul] + grub1[512 + u];
        float xh = mx[2][bl][ul];
        float z = 1.f / (1.f + __expf(-xz));
        float r = 1.f / (1.f + __expf(-xr));
        float hh = fast_tanh(xh + r * grub1[1024 + u]);
        so[(size_t)b * 512 + u] = f2bf((1.f - z) * hh);
      }
      __syncthreads();
    }
    grid.sync();
  }
}

extern "C" void kernel_launch(void* const* d_in, const int* in_sizes, int n_in,
                              void* d_out, int out_size, void* d_ws, size_t ws_size,
                              hipStream_t stream) {
  const float* img    = (const float*)d_in[0];
  const int*   target = (const int*)d_in[1];
  const float* W_fc   = (const float*)d_in[2];
  const float* b_fc   = (const float*)d_in[3];
  const float* W1     = (const float*)d_in[4];
  const float* b1     = (const float*)d_in[5];
  const float* W2     = (const float*)d_in[6];
  const float* b2     = (const float*)d_in[7];
  const float* V      = (const float*)d_in[8];
  const float* bV     = (const float*)d_in[9];
  const float* emb    = (const float*)d_in[10];
  const float* gru_k  = (const float*)d_in[11];
  /* d_in[12] = gru_rk: dead (h0 == 0 every step) */
  const float* gru_b  = (const float*)d_in[13];
  const float* fc1_w  = (const float*)d_in[14];
  const float* fc1_b  = (const float*)d_in[15];
  const float* fc2_w  = (const float*)d_in[16];
  const float* fc2_b  = (const float*)d_in[17];

  // ---- d_ws layout: transposed bf16 weights + tiny buffers ----
  char* wsb = (char*)d_ws;
  size_t off = 0;
  auto alloc = [&](size_t bytes) {
    char* p = wsb + off;
    off += (bytes + 255) & ~(size_t)255;
    return p;
  };
  ushort* W_fcT = (ushort*)alloc((size_t)256 * 2048 * 2);   // 1.05 MB
  ushort* W1T   = (ushort*)alloc((size_t)512 * 256 * 2);    // 0.26 MB
  ushort* W2T   = (ushort*)alloc((size_t)512 * 512 * 2);    // 0.52 MB
  ushort* gruT  = (ushort*)alloc((size_t)1536 * 512 * 2);   // 1.57 MB
  ushort* fc1T  = (ushort*)alloc((size_t)512 * 512 * 2);    // 0.52 MB
  ushort* fc2T  = (ushort*)alloc((size_t)5000 * 512 * 2);   // 5.12 MB
  ushort* ctx   = (ushort*)alloc((size_t)128 * 256 * 2);    // 64 KB
  ushort* hid2ws = (ushort*)alloc((size_t)6016 * 512 * 2);  // 6.16 MB

  // ---- big bf16 intermediates inside d_out (fp32 out: 120.3 MB; ~22 MB used).
  // All dead before the final fc2 GEMM overwrites every element of d_out;
  // fc2 reads only hid2ws (in d_ws, no overlap with its writes).
  char* ob = (char*)d_out;
  ushort* features = (ushort*)(ob);                               // 8192x256  = 4.19 MB
  ushort* featW1   = (ushort*)(ob + (size_t)4194304);             // 8192x512  = 8.39 MB
  ushort* states   = (ushort*)(ob + (size_t)12582912);            // 48x128x512= 6.29 MB
  ushort* embA     = (ushort*)(ob + (size_t)18874368);            // 6016x256  = 3.08 MB

  dim3 tb(32, 8);
  transpose_f2b<<<dim3(8, 64), tb, 0, stream>>>(W_fc, W_fcT, 2048, 256);
  transpose_f2b<<<dim3(16, 8), tb, 0, stream>>>(W1, W1T, 256, 512);
  transpose_f2b<<<dim3(16, 16), tb, 0, stream>>>(W2, W2T, 512, 512);
  transpose_f2b<<<dim3(48, 16), tb, 0, stream>>>(gru_k, gruT, 512, 1536);
  transpose_f2b<<<dim3(16, 16), tb, 0, stream>>>(fc1_w, fc1T, 512, 512);
  transpose_f2b<<<dim3(157, 16), tb, 0, stream>>>(fc2_w, fc2T, 512, 5000);

  embed_gather<<<6016, 256, 0, stream>>>(target, emb, embA);

  // encoder: features = relu(img @ W_fc + b_fc)   (8192,256) K=2048, fp32 A
  gemm128<<<dim3(2, 64), 256, 0, stream>>>(img, W_fcT, b_fc, features,
                                           8192, 256, 2048, 256, 1 | 8);
  // featW1 = features @ W1 + b1                   (8192,512) K=256
  gemm128<<<dim3(4, 64), 256, 0, stream>>>(features, W1T, b1, featW1,
                                           8192, 512, 256, 512, 0);

  hipMemsetAsync(states, 0, (size_t)128 * 512 * 2, stream);  // hidden_0 = 0

  // persistent cooperative loop (replaces 94 launches)
  {
    const ushort *a0 = featW1, *a1 = features, *a2 = W2T, *a6 = embA, *a7 = gruT;
    const float *a3 = b2, *a4 = V, *a5 = bV, *a8 = gru_b, *a9 = gru_b + 1536;
    ushort *a10 = states, *a11 = ctx;
    void* kargs[] = {&a0, &a1, &a2, &a3, &a4, &a5, &a6, &a7, &a8, &a9, &a10, &a11};
    hipLaunchCooperativeKernel((void*)step_loop, dim3(128), dim3(256), kargs, 0, stream);
  }

  // fc1 over all steps: (6016,512) K=512
  gemm128<<<dim3(4, 47), 256, 0, stream>>>(states + (size_t)128 * 512, fc1T, fc1_b,
                                           hid2ws, 6016, 512, 512, 512, 0);
  // fc2 -> d_out fp32 with (t,b)->(b,t) remap: (6016,5000) K=512
  gemm128<<<dim3(40, 47), 256, 0, stream>>>(hid2ws, fc2T, fc2_b, d_out,
                                            6016, 5000, 512, 5000, 2 | 4);
}

// Round 3
// 1757.138 us; speedup vs baseline: 1.9726x; 1.9726x over previous
//
#include <hip/hip_runtime.h>

typedef __attribute__((ext_vector_type(8))) short short8;
typedef __attribute__((ext_vector_type(4))) float f32x4;

__device__ __forceinline__ float bf2f(ushort u) {
  union { unsigned int i; float f; } x; x.i = ((unsigned int)u) << 16; return x.f;
}
__device__ __forceinline__ ushort f2bf(float f) {
  union { float f; unsigned int i; } x; x.f = f;
  unsigned int i = x.i + 0x7fffu + ((x.i >> 16) & 1u);
  return (ushort)(i >> 16);
}
__device__ __forceinline__ float blo(unsigned int u) {  // bf16 in low 16 bits
  union { unsigned int i; float f; } x; x.i = u << 16; return x.f;
}
__device__ __forceinline__ float bhi(unsigned int u) {  // bf16 in high 16 bits
  union { unsigned int i; float f; } x; x.i = u & 0xffff0000u; return x.f;
}
__device__ __forceinline__ float fast_tanh(float x) {
  x = fminf(fmaxf(x, -15.f), 15.f);
  float e = __expf(2.f * x);
  return __fdividef(e - 1.f, e + 1.f);
}
__device__ __forceinline__ float sigm(float x) { return 1.f / (1.f + __expf(-x)); }

// -------- transpose fp32 -> bf16, out[c][r] = bf16(in[r][c]) --------
__global__ void transpose_f2b(const float* __restrict__ in, ushort* __restrict__ out,
                              int R, int C) {
  __shared__ ushort tile[32][33];
  int c0 = blockIdx.x * 32, r0 = blockIdx.y * 32;
  int tx = threadIdx.x, ty = threadIdx.y;  // block (32,8)
  for (int i = 0; i < 32; i += 8) {
    int r = r0 + ty + i, c = c0 + tx;
    if (r < R && c < C) tile[ty + i][tx] = f2bf(in[(size_t)r * C + c]);
  }
  __syncthreads();
  for (int i = 0; i < 32; i += 8) {
    int c = c0 + ty + i, r = r0 + tx;
    if (r < R && c < C) out[(size_t)c * R + r] = tile[tx][ty + i];
  }
}

// -------- gather embedded tokens (fp32 emb -> bf16): embA[t*128+b][:] --------
__global__ void embed_gather(const int* __restrict__ target, const float* __restrict__ emb,
                             ushort* __restrict__ embA) {
  int m = blockIdx.x;            // 0..6015
  int t = m >> 7, b = m & 127;
  int tok = (t == 0) ? 1 : target[b * 48 + t];
  embA[(size_t)m * 256 + threadIdx.x] = f2bf(emb[(size_t)tok * 256 + threadIdx.x]);
}

// ---------------- 128x128 LDS-staged MFMA GEMM ----------------
// C = act(A[M,K] @ B^T + bias), B rows at BT + row*bstride (k-contiguous).
// flags: 1=relu, 2=store fp32, 4=remap rows m=t*128+b -> out row b*47+t, 8=A is fp32
__global__ __launch_bounds__(256) void gemm128(
    const void* __restrict__ Ap, const ushort* __restrict__ BT,
    const float* __restrict__ bias, void* __restrict__ Cout,
    int M, int N, int K, int NrowsB, int bstride, int flags) {
  __shared__ ushort lA[128 * 32];
  __shared__ ushort lB[128 * 32];
  int tid = threadIdx.x;
  int wave = tid >> 6, lane = tid & 63;
  int q = lane >> 4, l16 = lane & 15;
  int wr = wave >> 1, wc = wave & 1;
  int m0 = blockIdx.y * 128, n0 = blockIdx.x * 128;
  f32x4 acc[4][4];
#pragma unroll
  for (int i = 0; i < 4; ++i)
#pragma unroll
    for (int j = 0; j < 4; ++j) acc[i][j] = (f32x4){0.f, 0.f, 0.f, 0.f};
  int r0 = tid >> 2, cc0 = (tid & 3) * 8;
  int r1 = r0 + 64, cc1 = cc0;
  int rb0 = n0 + r0; if (rb0 >= NrowsB) rb0 = NrowsB - 1;
  int rb1 = n0 + r1; if (rb1 >= NrowsB) rb1 = NrowsB - 1;
  for (int k = 0; k < K; k += 32) {
    short8 va0, va1, vb0, vb1;
    if (flags & 8) {
      const float* s0 = (const float*)Ap + (size_t)(m0 + r0) * K + k + cc0;
      const float* s1 = (const float*)Ap + (size_t)(m0 + r1) * K + k + cc1;
      short8 t0, t1;
#pragma unroll
      for (int e = 0; e < 8; ++e) { t0[e] = (short)f2bf(s0[e]); t1[e] = (short)f2bf(s1[e]); }
      va0 = t0; va1 = t1;
    } else {
      va0 = *(const short8*)((const ushort*)Ap + (size_t)(m0 + r0) * K + k + cc0);
      va1 = *(const short8*)((const ushort*)Ap + (size_t)(m0 + r1) * K + k + cc1);
    }
    vb0 = *(const short8*)(BT + (size_t)rb0 * bstride + k + cc0);
    vb1 = *(const short8*)(BT + (size_t)rb1 * bstride + k + cc1);
    __syncthreads();
    *(short8*)&lA[r0 * 32 + cc0] = va0;
    *(short8*)&lA[r1 * 32 + cc1] = va1;
    *(short8*)&lB[r0 * 32 + cc0] = vb0;
    *(short8*)&lB[r1 * 32 + cc1] = vb1;
    __syncthreads();
    short8 af[4], bfr[4];
#pragma unroll
    for (int i = 0; i < 4; ++i)
      af[i] = *(const short8*)&lA[(wr * 64 + i * 16 + l16) * 32 + q * 8];
#pragma unroll
    for (int j = 0; j < 4; ++j)
      bfr[j] = *(const short8*)&lB[(wc * 64 + j * 16 + l16) * 32 + q * 8];
#pragma unroll
    for (int i = 0; i < 4; ++i)
#pragma unroll
      for (int j = 0; j < 4; ++j)
        acc[i][j] = __builtin_amdgcn_mfma_f32_16x16x32_bf16(af[i], bfr[j], acc[i][j], 0, 0, 0);
  }
#pragma unroll
  for (int i = 0; i < 4; ++i)
#pragma unroll
    for (int j = 0; j < 4; ++j)
#pragma unroll
      for (int r = 0; r < 4; ++r) {
        int gr = m0 + wr * 64 + i * 16 + q * 4 + r;  // D row = quad*4 + reg [m89/m91]
        int gc = n0 + wc * 64 + j * 16 + l16;        // D col = lane&15
        if (gc >= N) continue;
        float v = acc[i][j][r];
        if (bias) v += bias[gc];
        if (flags & 1) v = fmaxf(v, 0.f);
        size_t orow = (size_t)gr;
        if (flags & 4) { int t = gr >> 7, bb = gr & 127; orow = (size_t)bb * 47 + t; }
        if (flags & 2) ((float*)Cout)[orow * (size_t)N + gc] = v;
        else ((ushort*)Cout)[orow * (size_t)N + gc] = f2bf(v);
      }
}

// ---------------- persistent per-row loop: NO grid syncs, NO per-step launches ----------------
// Block b owns batch row b for all 47 steps (recurrence is batch-row-local).
// GRU input factored: x@gru_k = sum_l attnw[l]*featK[b,l,:] + xE[t*128+b,:]  (both precomputed).
// state lives in LDS (f32) across steps; written to global bf16 for fc1.
__global__ __launch_bounds__(512) void row_loop(
    const ushort* __restrict__ featW1,   // (8192,512) bf16, row = b*64+l
    const ushort* __restrict__ W2T,      // (512,512) bf16, row u = col u of W2 (k-contig)
    const float* __restrict__ b2,        // (512)
    const float* __restrict__ V,         // (512)
    const float* __restrict__ bV,        // (1)
    const ushort* __restrict__ featK,    // (8192,1536) bf16 = features @ gru_k[0:256]
    const ushort* __restrict__ xE,       // (6016,1536) bf16 = embA @ gru_k[256:512]
    const float* __restrict__ grub0,     // (1536)
    const float* __restrict__ grub1,     // (1536)
    ushort* __restrict__ states) {       // (48,128,512) bf16; rows 1..47 written
  int b = blockIdx.x, tid = threadIdx.x;
  __shared__ __align__(16) float stf[512];
  __shared__ float hw2p[520], Vvp[520];   // padded idx u+(u>>6): stride-64 reads hit distinct banks
  __shared__ float sc[64], attnw[64];
  // t-invariant hoists
  float b2r = b2[tid];
  float g0z = grub0[tid], g0r = grub0[512 + tid], g0h = grub0[1024 + tid];
  float g1z = grub1[tid], g1r = grub1[512 + tid], g1h = grub1[1024 + tid];
  float bVr = bV[0];
  Vvp[tid + (tid >> 6)] = V[tid];
  stf[tid] = 0.f;                         // hidden_0 = 0
  const uint4* w2row = (const uint4*)(W2T + (size_t)tid * 512);  // 64 uint4 = 512 bf16
  int l = tid >> 3, part = tid & 7;       // 8 threads per region l, 64 u each
  const short8* fw8 = (const short8*)(featW1 + ((size_t)(b * 64 + l)) * 512 + part * 64);
  const ushort* fkb = featK + (size_t)b * 64 * 1536 + tid;
  __syncthreads();

#pragma unroll 1
  for (int t = 0; t < 47; ++t) {
    // ---- phase 1: hw2[u=tid] = state . W2[:,u] + b2[u] ----
    {
      float s0 = 0.f, s1 = 0.f;
#pragma unroll 8
      for (int k8 = 0; k8 < 64; ++k8) {
        uint4 w = w2row[k8];
        const float4* sp = (const float4*)(stf + k8 * 8);  // wave-uniform -> LDS broadcast
        float4 sA = sp[0], sB = sp[1];
        s0 += blo(w.x) * sA.x + bhi(w.x) * sA.y;
        s1 += blo(w.y) * sA.z + bhi(w.y) * sA.w;
        s0 += blo(w.z) * sB.x + bhi(w.z) * sB.y;
        s1 += blo(w.w) * sB.z + bhi(w.w) * sB.w;
      }
      hw2p[tid + (tid >> 6)] = s0 + s1 + b2r;
    }
    __syncthreads();
    // ---- phase 2: scores; 8 threads per l, 64 u each ----
    {
      float s = 0.f;
#pragma unroll 2
      for (int u8 = 0; u8 < 8; ++u8) {
        short8 fv = fw8[u8];
        int ub = part * 64 + u8 * 8;
        int pi = ub + part;              // padded index base
#pragma unroll
        for (int e = 0; e < 8; ++e) {
          float x = bf2f((ushort)fv[e]) + hw2p[pi + e];
          s += fast_tanh(x) * Vvp[pi + e];
        }
      }
      s += __shfl_xor(s, 1);
      s += __shfl_xor(s, 2);
      s += __shfl_xor(s, 4);
      if (part == 0) sc[l] = s + bVr;
    }
    __syncthreads();
    // ---- phase 3: softmax over L=64 (wave 0) ----
    if (tid < 64) {
      float v = sc[tid], m = v;
      for (int o = 32; o; o >>= 1) m = fmaxf(m, __shfl_xor(m, o));
      float e = __expf(v - m), ss = e;
      for (int o = 32; o; o >>= 1) ss += __shfl_xor(ss, o);
      attnw[tid] = e / ss;
    }
    __syncthreads();
    // ---- phase 4: GRU gates; thread tid owns unit u=tid ----
    {
      const ushort* xe = xE + ((size_t)(t * 128 + b)) * 1536;
      float az = bf2f(xe[tid]), ar = bf2f(xe[512 + tid]), ah = bf2f(xe[1024 + tid]);
      const ushort* fk = fkb;
#pragma unroll 4
      for (int l2 = 0; l2 < 64; ++l2) {
        float a = attnw[l2];             // uniform -> LDS broadcast
        az += a * bf2f(fk[0]);
        ar += a * bf2f(fk[512]);
        ah += a * bf2f(fk[1024]);
        fk += 1536;
      }
      float z = sigm(az + g0z + g1z);
      float r = sigm(ar + g0r + g1r);
      float hh = fast_tanh(ah + g0h + r * g1h);
      float st = (1.f - z) * hh;
      stf[tid] = st;                     // no reader between phase-1 barrier and here
      states[((size_t)(t + 1) * 128 + b) * 512 + tid] = f2bf(st);
    }
    __syncthreads();
  }
}

extern "C" void kernel_launch(void* const* d_in, const int* in_sizes, int n_in,
                              void* d_out, int out_size, void* d_ws, size_t ws_size,
                              hipStream_t stream) {
  const float* img    = (const float*)d_in[0];
  const int*   target = (const int*)d_in[1];
  const float* W_fc   = (const float*)d_in[2];
  const float* b_fc   = (const float*)d_in[3];
  const float* W1     = (const float*)d_in[4];
  const float* b1     = (const float*)d_in[5];
  const float* W2     = (const float*)d_in[6];
  const float* b2     = (const float*)d_in[7];
  const float* V      = (const float*)d_in[8];
  const float* bV     = (const float*)d_in[9];
  const float* emb    = (const float*)d_in[10];
  const float* gru_k  = (const float*)d_in[11];
  /* d_in[12] = gru_rk: dead (h0 == 0 every step) */
  const float* gru_b  = (const float*)d_in[13];
  const float* fc1_w  = (const float*)d_in[14];
  const float* fc1_b  = (const float*)d_in[15];
  const float* fc2_w  = (const float*)d_in[16];
  const float* fc2_b  = (const float*)d_in[17];

  // ---- d_ws layout (~15.2 MB): transposed bf16 weights ----
  char* wsb = (char*)d_ws;
  size_t off = 0;
  auto alloc = [&](size_t bytes) {
    char* p = wsb + off;
    off += (bytes + 255) & ~(size_t)255;
    return p;
  };
  ushort* W_fcT  = (ushort*)alloc((size_t)256 * 2048 * 2);   // 1.05 MB
  ushort* W1T    = (ushort*)alloc((size_t)512 * 256 * 2);    // 0.26 MB
  ushort* W2T    = (ushort*)alloc((size_t)512 * 512 * 2);    // 0.52 MB
  ushort* gruT   = (ushort*)alloc((size_t)1536 * 512 * 2);   // 1.57 MB (row u' = gru_k[:,u'])
  ushort* fc1T   = (ushort*)alloc((size_t)512 * 512 * 2);    // 0.52 MB
  ushort* fc2T   = (ushort*)alloc((size_t)5000 * 512 * 2);   // 5.12 MB
  ushort* hid2ws = (ushort*)alloc((size_t)6016 * 512 * 2);   // 6.16 MB

  // ---- bf16 intermediates inside d_out (120.3 MB; 65.6 MB used, all dead before
  // the final fc2 GEMM overwrites d_out; fc2 reads only hid2ws/fc2T in d_ws). ----
  char* ob = (char*)d_out;
  ushort* features = (ushort*)(ob);                               // 8192x256   4.19 MB
  ushort* featW1   = (ushort*)(ob + (size_t)4194304);             // 8192x512   8.39 MB
  ushort* states   = (ushort*)(ob + (size_t)12582912);            // 48x128x512 6.29 MB
  ushort* embA     = (ushort*)(ob + (size_t)18874368);            // 6016x256   3.08 MB
  ushort* featK    = (ushort*)(ob + (size_t)21954560);            // 8192x1536 25.17 MB
  ushort* xE       = (ushort*)(ob + (size_t)47120384);            // 6016x1536 18.48 MB -> ends 65.6 MB

  dim3 tb(32, 8);
  transpose_f2b<<<dim3(8, 64), tb, 0, stream>>>(W_fc, W_fcT, 2048, 256);
  transpose_f2b<<<dim3(16, 8), tb, 0, stream>>>(W1, W1T, 256, 512);
  transpose_f2b<<<dim3(16, 16), tb, 0, stream>>>(W2, W2T, 512, 512);
  transpose_f2b<<<dim3(48, 16), tb, 0, stream>>>(gru_k, gruT, 512, 1536);
  transpose_f2b<<<dim3(16, 16), tb, 0, stream>>>(fc1_w, fc1T, 512, 512);
  transpose_f2b<<<dim3(157, 16), tb, 0, stream>>>(fc2_w, fc2T, 512, 5000);

  embed_gather<<<6016, 256, 0, stream>>>(target, emb, embA);

  // encoder: features = relu(img @ W_fc + b_fc)   (8192,256) K=2048, fp32 A
  gemm128<<<dim3(2, 64), 256, 0, stream>>>(img, W_fcT, b_fc, features,
                                           8192, 256, 2048, 256, 2048, 1 | 8);
  // featW1 = features @ W1 + b1                   (8192,512) K=256
  gemm128<<<dim3(4, 64), 256, 0, stream>>>(features, W1T, b1, featW1,
                                           8192, 512, 256, 512, 256, 0);
  // featK = features @ gru_k[0:256,:]             (8192,1536) K=256 (gruT rows, stride 512)
  gemm128<<<dim3(12, 64), 256, 0, stream>>>(features, gruT, nullptr, featK,
                                            8192, 1536, 256, 1536, 512, 0);
  // xE = embA @ gru_k[256:512,:]                  (6016,1536) K=256 (gruT rows offset +256)
  gemm128<<<dim3(12, 47), 256, 0, stream>>>(embA, gruT + 256, nullptr, xE,
                                            6016, 1536, 256, 1536, 512, 0);

  // persistent per-row recurrence: one launch, zero grid syncs
  row_loop<<<128, 512, 0, stream>>>(featW1, W2T, b2, V, bV, featK, xE,
                                    gru_b, gru_b + 1536, states);

  // fc1 over all steps: (6016,512) K=512
  gemm128<<<dim3(4, 47), 256, 0, stream>>>(states + (size_t)128 * 512, fc1T, fc1_b,
                                           hid2ws, 6016, 512, 512, 512, 512, 0);
  // fc2 -> d_out fp32 with (t,b)->(b,t) remap: (6016,5000) K=512
  gemm128<<<dim3(40, 47), 256, 0, stream>>>(hid2ws, fc2T, fc2_b, d_out,
                                            6016, 5000, 512, 5000, 512, 2 | 4);
}